// Round 11
// baseline (461.680 us; speedup 1.0000x reference)
//
#include <hip/hip_runtime.h>
#include <hip/hip_bf16.h>
#include <math.h>

// Problem constants
#define B_  64
#define T_  2048
#define DEC_ 1024
#define ENC_ 512
#define ATT_ 128
#define LOC_ 32
#define KW_  31

typedef __attribute__((ext_vector_type(8))) short short8;
typedef __attribute__((ext_vector_type(4))) float f32x4;
typedef __attribute__((ext_vector_type(4))) unsigned int u32x4;

__device__ inline unsigned short bf16_rn(float x) {
    unsigned int u = __builtin_bit_cast(unsigned int, x);
    unsigned int r = u + 0x7fffu + ((u >> 16) & 1u);
    return (unsigned short)(r >> 16);
}
__device__ inline float bf16_to_f(unsigned short h) {
    unsigned int u = ((unsigned int)h) << 16;
    return __builtin_bit_cast(float, u);
}
// Split 8 floats into hi/lo bf16 (bit-exact add-based RNE, packed pairs).
__device__ inline void cvt_split8_exact(const float* f, short8& hi8, short8& lo8) {
    u32x4 hw, lw;
    #pragma unroll
    for (int p = 0; p < 4; ++p) {
        float a = f[2 * p], b2 = f[2 * p + 1];
        unsigned u0 = __builtin_bit_cast(unsigned, a);
        unsigned u1 = __builtin_bit_cast(unsigned, b2);
        unsigned r0 = u0 + 0x7fffu + ((u0 >> 16) & 1u);
        unsigned r1 = u1 + 0x7fffu + ((u1 >> 16) & 1u);
        hw[p] = (r0 >> 16) | (r1 & 0xffff0000u);
        float d0 = a  - __builtin_bit_cast(float, r0 & 0xffff0000u);
        float d1 = b2 - __builtin_bit_cast(float, r1 & 0xffff0000u);
        unsigned v0 = __builtin_bit_cast(unsigned, d0);
        unsigned v1 = __builtin_bit_cast(unsigned, d1);
        unsigned s0 = v0 + 0x7fffu + ((v0 >> 16) & 1u);
        unsigned s1 = v1 + 0x7fffu + ((v1 >> 16) & 1u);
        lw[p] = (s0 >> 16) | (s1 & 0xffff0000u);
    }
    hi8 = __builtin_bit_cast(short8, hw);
    lo8 = __builtin_bit_cast(short8, lw);
}

// ---------------------------------------------------------------------------
// K1: prep (unchanged, R1-verified: Bp[(k>>5)*4096 + n*32 + (k&31)])
// ---------------------------------------------------------------------------
__global__ __launch_bounds__(256) void prep_kernel(
    const float* __restrict__ query, const float* __restrict__ Q_w,
    const float* __restrict__ Q_b, const float* __restrict__ conv_w,
    const float* __restrict__ loc_proj_w, const float* __restrict__ V_w,
    float* __restrict__ qbuf,
    unsigned short* __restrict__ Bph, unsigned short* __restrict__ Bpl,
    unsigned short* __restrict__ effh, unsigned short* __restrict__ effl)
{
    int bi = blockIdx.x, tid = threadIdx.x;
    if (bi < 256) {
        int b = bi >> 2, grp = bi & 3;
        __shared__ float sq[DEC_];
        *(float4*)(&sq[tid * 4]) = *(const float4*)(query + (size_t)b * DEC_ + tid * 4);
        __syncthreads();
        int w = tid >> 6, lane = tid & 63;
        int a0 = grp * 32 + w * 8;
        for (int p = 0; p < 4; ++p) {
            int a = a0 + 2 * p;
            const float* r0 = Q_w + (size_t)a * DEC_;
            const float* r1 = r0 + DEC_;
            float s0 = 0.f, s1 = 0.f;
            #pragma unroll
            for (int i = 0; i < 4; ++i) {
                float4 q0 = *(const float4*)(r0 + i * 256 + lane * 4);
                float4 q1 = *(const float4*)(r1 + i * 256 + lane * 4);
                float4 xq = *(const float4*)(sq + i * 256 + lane * 4);
                s0 += q0.x * xq.x + q0.y * xq.y + q0.z * xq.z + q0.w * xq.w;
                s1 += q1.x * xq.x + q1.y * xq.y + q1.z * xq.z + q1.w * xq.w;
            }
            #pragma unroll
            for (int m = 32; m >= 1; m >>= 1) {
                s0 += __shfl_xor(s0, m, 64);
                s1 += __shfl_xor(s1, m, 64);
            }
            if (lane == 0) {
                qbuf[b * ATT_ + a]     = s0 + Q_b[a];
                qbuf[b * ATT_ + a + 1] = s1 + Q_b[a + 1];
            }
        }
    } else if (bi == 256) {
        __shared__ float slp[ATT_ * LOC_];
        __shared__ float scw[LOC_ * KW_];
        for (int i = tid; i < ATT_ * LOC_; i += 256) slp[i] = loc_proj_w[i];
        for (int i = tid; i < LOC_ * KW_; i += 256) scw[i] = conv_w[i];
        __syncthreads();
        if (tid < ATT_) {
            int n = tid;
            for (int k = 0; k < 32; ++k) {
                float s = 0.f;
                if (k < KW_)
                    #pragma unroll
                    for (int c = 0; c < LOC_; ++c)
                        s += slp[n * LOC_ + c] * scw[c * KW_ + k];
                unsigned short h = bf16_rn(s);
                effh[n * 32 + k] = h;
                effl[n * 32 + k] = bf16_rn(s - bf16_to_f(h));
            }
        }
    } else {
        int g0 = (bi - 257) * 512;
        #pragma unroll
        for (int p = 0; p < 2; ++p) {
            int gi = g0 + p * 256 + tid;
            int n  = gi >> 7;
            int kq = (gi & 127) * 4;
            float4 v = ((const float4*)V_w)[gi];
            ushort4 h4, l4;
            h4.x = bf16_rn(v.x); l4.x = bf16_rn(v.x - bf16_to_f(h4.x));
            h4.y = bf16_rn(v.y); l4.y = bf16_rn(v.y - bf16_to_f(h4.y));
            h4.z = bf16_rn(v.z); l4.z = bf16_rn(v.z - bf16_to_f(h4.z));
            h4.w = bf16_rn(v.w); l4.w = bf16_rn(v.w - bf16_to_f(h4.w));
            int dst = (kq >> 5) * 4096 + n * 32 + (kq & 31);
            *(ushort4*)(Bph + dst) = h4;
            *(ushort4*)(Bpl + dst) = l4;
        }
    }
}

// ---------------------------------------------------------------------------
// K2 (FUSED, 8-wave N-split + LDS A-fragment share):
//  512 threads = 8 waves as (wr 0..3) x (wc 0..1). Wave: M=32 rows, N=64.
//  Per chunk: each wave cvt's 16 rows of A ONCE -> double-buffered LDS frag
//  store; all waves ds_read_b128 their fragments; B (half per wave) from L2/L1.
//  Raw s_barrier + lgkmcnt(0) only (vmem prefetch survives the barrier).
//  acc chains BIT-IDENTICAL to R1. Flash local softmax + partial context
//  numerics preserved (context fold association identical to R1).
// ---------------------------------------------------------------------------
__global__ __launch_bounds__(512, 4) void energy_ctx_kernel(
    const float* __restrict__ values, const float* __restrict__ cum,
    const float* __restrict__ qbuf,
    const unsigned short* __restrict__ Bph, const unsigned short* __restrict__ Bpl,
    const unsigned short* __restrict__ effh, const unsigned short* __restrict__ effl,
    const float* __restrict__ vw, const unsigned char* __restrict__ mask,
    float* __restrict__ wU, float* __restrict__ bstats,
    float* __restrict__ ctxpart)
{
    __shared__ unsigned short sAh[2][4096];   // A hi frags, dbuf (8 KB each)
    __shared__ unsigned short sAl[2][4096];   // A lo frags
    __shared__ float sx[160];
    __shared__ float sep[2][128];
    __shared__ float se[128];
    __shared__ float red[512];

    const int tid = threadIdx.x;
    const int bx  = blockIdx.x;
    const int b   = bx >> 4;
    const int t0  = (bx & 15) * 128;

    if (tid < 160) {
        int g = t0 - 15 + tid;
        sx[tid] = (g >= 0 && g < T_) ? cum[b * T_ + g] : 0.f;
    }

    const int w      = tid >> 6;
    const int lane   = tid & 63;
    const int lane15 = lane & 15;
    const int quad   = lane >> 4;
    const int wr     = w >> 1;    // M-quarter (rows wr*32..+31)
    const int wc     = w & 1;     // N-half  (cols wc*64..+63)

    f32x4 acc[2][4];
    #pragma unroll
    for (int i = 0; i < 2; ++i)
        #pragma unroll
        for (int j = 0; j < 4; ++j) acc[i][j] = (f32x4){0.f, 0.f, 0.f, 0.f};

    // writer role: this wave converts rows w*16..+15 (each row once per block)
    const float* wsrc = values + ((size_t)b * T_ + t0 + w * 16 + lane15) * ENC_ + quad * 8;
    // B base for this wave's N-half
    const unsigned short* bbh = Bph + wc * 2048 + lane15 * 32 + quad * 8;
    const unsigned short* bbl = Bpl + wc * 2048 + lane15 * 32 + quad * 8;

    // A fp32 prefetch regs: pA[p] holds the next chunk of parity p
    float4 pA[2][2];
    pA[0][0] = *(const float4*)(wsrc);
    pA[0][1] = *(const float4*)(wsrc + 4);
    pA[1][0] = *(const float4*)(wsrc + 32);
    pA[1][1] = *(const float4*)(wsrc + 36);

    // prologue: cvt chunk 0 -> buf 0
    {
        float fb[8] = {pA[0][0].x, pA[0][0].y, pA[0][0].z, pA[0][0].w,
                       pA[0][1].x, pA[0][1].y, pA[0][1].z, pA[0][1].w};
        short8 h8, l8;
        cvt_split8_exact(fb, h8, l8);
        *(short8*)&sAh[0][(w * 64 + lane) * 8] = h8;
        *(short8*)&sAl[0][(w * 64 + lane) * 8] = l8;
    }
    __syncthreads();   // one full sync: sx + buf0 ready, clean slate

    #pragma unroll
    for (int c = 0; c < 16; ++c) {
        const int cur = c & 1;
        // 1) issue A fp32 for chunk c+2 (re-using the parity slot consumed at c)
        if (c + 2 < 16) {
            pA[cur][0] = *(const float4*)(wsrc + (c + 2) * 32);
            pA[cur][1] = *(const float4*)(wsrc + (c + 2) * 32 + 4);
        }
        __builtin_amdgcn_sched_barrier(0);

        // 2) read this wave's A fragments for chunk c from LDS
        short8 ah[2], al[2];
        #pragma unroll
        for (int i = 0; i < 2; ++i) {
            ah[i] = *(const short8*)&sAh[cur][((wr * 2 + i) * 64 + lane) * 8];
            al[i] = *(const short8*)&sAl[cur][((wr * 2 + i) * 64 + lane) * 8];
        }

        // 3) cvt chunk c+1 from regs -> other buffer
        if (c + 1 < 16) {
            float fb[8] = {pA[cur ^ 1][0].x, pA[cur ^ 1][0].y,
                           pA[cur ^ 1][0].z, pA[cur ^ 1][0].w,
                           pA[cur ^ 1][1].x, pA[cur ^ 1][1].y,
                           pA[cur ^ 1][1].z, pA[cur ^ 1][1].w};
            short8 h8, l8;
            cvt_split8_exact(fb, h8, l8);
            *(short8*)&sAh[cur ^ 1][(w * 64 + lane) * 8] = h8;
            *(short8*)&sAl[cur ^ 1][(w * 64 + lane) * 8] = l8;
        }

        // 4) B (this wave's 64-col half) in two j-pairs + MFMA
        const int chunk = (c >> 0) * 0 + (c * 0);   // (placeholder, see below)
        const int coff  = (c) * 4096;               // (kc>>5)*4096 with kc=c*32
        #pragma unroll
        for (int jp = 0; jp < 2; ++jp) {
            short8 bh[2], bl[2];
            #pragma unroll
            for (int u = 0; u < 2; ++u) {
                bh[u] = *(const short8*)(bbh + coff + (jp * 2 + u) * 512);
                bl[u] = *(const short8*)(bbl + coff + (jp * 2 + u) * 512);
            }
            #pragma unroll
            for (int u = 0; u < 2; ++u)
                #pragma unroll
                for (int i = 0; i < 2; ++i) {
                    acc[i][jp * 2 + u] = __builtin_amdgcn_mfma_f32_16x16x32_bf16(ah[i], bh[u], acc[i][jp * 2 + u], 0, 0, 0);
                    acc[i][jp * 2 + u] = __builtin_amdgcn_mfma_f32_16x16x32_bf16(ah[i], bl[u], acc[i][jp * 2 + u], 0, 0, 0);
                    acc[i][jp * 2 + u] = __builtin_amdgcn_mfma_f32_16x16x32_bf16(al[i], bh[u], acc[i][jp * 2 + u], 0, 0, 0);
                }
        }

        // 5) LDS-only fence + barrier (vmem prefetches stay in flight)
        if (c + 1 < 16) {
            __builtin_amdgcn_sched_barrier(0);
            asm volatile("s_waitcnt lgkmcnt(0)" ::: "memory");
            __builtin_amdgcn_s_barrier();
        }
        (void)chunk;
    }

    // ---- loc conv as MFMA: A' Toeplitz built from sx in-register ----
    {
        short8 ah[2], al[2];
        #pragma unroll
        for (int i = 0; i < 2; ++i) {
            int base = wr * 32 + i * 16 + lane15 + quad * 8;
            float xv[8];
            #pragma unroll
            for (int j2 = 0; j2 < 8; ++j2) xv[j2] = sx[base + j2];
            cvt_split8_exact(xv, ah[i], al[i]);
        }
        #pragma unroll
        for (int j = 0; j < 4; ++j) {
            int n = wc * 64 + j * 16 + lane15;
            short8 bh = *(const short8*)(effh + n * 32 + quad * 8);
            short8 bl = *(const short8*)(effl + n * 32 + quad * 8);
            #pragma unroll
            for (int i = 0; i < 2; ++i) {
                acc[i][j] = __builtin_amdgcn_mfma_f32_16x16x32_bf16(ah[i], bh, acc[i][j], 0, 0, 0);
                acc[i][j] = __builtin_amdgcn_mfma_f32_16x16x32_bf16(ah[i], bl, acc[i][j], 0, 0, 0);
                acc[i][j] = __builtin_amdgcn_mfma_f32_16x16x32_bf16(al[i], bh, acc[i][j], 0, 0, 0);
            }
        }
    }

    // ---- energies: per-wave N-half partials -> sep, then combine + mask ----
    float qv[4], vv[4];
    #pragma unroll
    for (int j = 0; j < 4; ++j) {
        int n = wc * 64 + j * 16 + lane15;
        qv[j] = qbuf[b * ATT_ + n];
        vv[j] = vw[n];
    }
    #pragma unroll
    for (int i = 0; i < 2; ++i)
        #pragma unroll
        for (int r = 0; r < 4; ++r) {
            float s = 0.f;
            #pragma unroll
            for (int j = 0; j < 4; ++j)
                s += vv[j] * tanhf(acc[i][j][r] + qv[j]);
            #pragma unroll
            for (int m = 8; m >= 1; m >>= 1) s += __shfl_xor(s, m, 64);
            if (lane15 == 0)
                sep[wc][wr * 32 + i * 16 + quad * 4 + r] = s;
        }
    __syncthreads();

    if (tid < 128) {
        float ee = sep[0][tid] + sep[1][tid];
        if (mask[b * T_ + t0 + tid]) ee = -INFINITY;
        se[tid] = ee;
    }
    __syncthreads();

    // ---- local (chunk) max + sum (all waves redundantly) ----
    float e0 = se[lane * 2], e1 = se[lane * 2 + 1];
    float mx = fmaxf(e0, e1);
    #pragma unroll
    for (int m = 32; m >= 1; m >>= 1) mx = fmaxf(mx, __shfl_xor(mx, m, 64));
    float w0 = 0.f, w1 = 0.f;
    if (mx > -INFINITY) {
        w0 = expf(e0 - mx);
        w1 = expf(e1 - mx);
    }
    float sm = w0 + w1;
    #pragma unroll
    for (int m = 32; m >= 1; m >>= 1) sm += __shfl_xor(sm, m, 64);
    __syncthreads();

    if (w == 0) {
        se[lane * 2]     = w0;
        se[lane * 2 + 1] = w1;
        *(float2*)(wU + b * T_ + t0 + lane * 2) = make_float2(w0, w1);
        if (lane == 0)
            *(float2*)(bstats + bx * 2) = make_float2(mx, sm);
    }
    __syncthreads();

    // ---- partial context (chunk L2-resident); fold association == R1 ----
    {
        int tt = tid >> 8;               // 0..1 : t-half (rows 0-63 / 64-127)
        int e2 = (tid & 255) * 2;        // 256 threads * float2 = 512 cols
        const float* vp = values + ((size_t)b * T_ + t0 + tt * 64) * ENC_ + e2;
        float cx = 0.f, cy = 0.f;
        #pragma unroll 8
        for (int t = 0; t < 64; ++t) {
            float2 v = *(const float2*)(vp + (size_t)t * ENC_);
            float wv = se[tt * 64 + t];
            cx += wv * v.x; cy += wv * v.y;
        }
        if (tt == 1) *(float2*)&red[e2] = make_float2(cx, cy);
        __syncthreads();
        if (tt == 0) {
            float2 o = *(const float2*)&red[e2];
            *(float2*)(ctxpart + (size_t)bx * ENC_ + e2) =
                make_float2(cx + o.x, cy + o.y);
        }
    }
}

// ---------------------------------------------------------------------------
// K3: combine 16 chunk-partials per b (unchanged from R1)
// ---------------------------------------------------------------------------
__global__ __launch_bounds__(256) void combine_kernel(
    const float* __restrict__ bstats, const float* __restrict__ ctxpart,
    const float* __restrict__ wU, float* __restrict__ out)
{
    int b = blockIdx.x, tid = threadIdx.x;
    __shared__ float smx[16], ssm[16], ssc[16];
    if (tid < 16) {
        float2 st = *(const float2*)(bstats + (b * 16 + tid) * 2);
        smx[tid] = st.x; ssm[tid] = st.y;
    }
    __syncthreads();
    float M = -INFINITY;
    #pragma unroll
    for (int k = 0; k < 16; ++k) M = fmaxf(M, smx[k]);
    if (tid < 16)
        ssc[tid] = (smx[tid] > -INFINITY) ? expf(smx[tid] - M) : 0.f;
    __syncthreads();
    float S = 0.f;
    #pragma unroll
    for (int k = 0; k < 16; ++k) S += ssm[k] * ssc[k];
    float invS = 1.f / S;

    float* ctx  = out;
    float* wout = out + B_ * ENC_;

    float cx = 0.f, cy = 0.f;
    #pragma unroll
    for (int k = 0; k < 16; ++k) {
        float2 v = *(const float2*)(ctxpart + (size_t)(b * 16 + k) * ENC_ + tid * 2);
        cx += v.x * ssc[k]; cy += v.y * ssc[k];
    }
    *(float2*)(ctx + b * ENC_ + tid * 2) = make_float2(cx * invS, cy * invS);

    #pragma unroll
    for (int p = 0; p < 8; ++p) {
        int t = p * 256 + tid;
        wout[b * T_ + t] = wU[b * T_ + t] * ssc[t >> 7] * invS;
    }
}

// ---------------------------------------------------------------------------
extern "C" void kernel_launch(void* const* d_in, const int* in_sizes, int n_in,
                              void* d_out, int out_size, void* d_ws, size_t ws_size,
                              hipStream_t stream) {
    const float* query        = (const float*)d_in[0];
    const float* values       = (const float*)d_in[1];
    const float* cum          = (const float*)d_in[2];
    const unsigned char* mask = (const unsigned char*)d_in[3];
    const float* Q_w          = (const float*)d_in[4];
    const float* Q_b          = (const float*)d_in[5];
    const float* V_w          = (const float*)d_in[6];
    const float* conv_w       = (const float*)d_in[7];
    const float* loc_proj_w   = (const float*)d_in[8];
    const float* v_w          = (const float*)d_in[9];

    float* out = (float*)d_out;
    char*  ws  = (char*)d_ws;
    // ws layout (bytes):
    //  qbuf @0 (32 KB) | Bph @32768 (128 KB) | Bpl @163840 (128 KB)
    //  effh @294912 (8 KB) | effl @303104 (8 KB) | wU @311296 (512 KB)
    //  bstats @835584 (8 KB) | ctxpart @843776 (2 MB)
    float*          qbuf     = (float*)(ws);
    unsigned short* Bph      = (unsigned short*)(ws + 32768);
    unsigned short* Bpl      = (unsigned short*)(ws + 163840);
    unsigned short* effh     = (unsigned short*)(ws + 294912);
    unsigned short* effl     = (unsigned short*)(ws + 303104);
    float*          wU       = (float*)(ws + 311296);
    float*          bstats   = (float*)(ws + 835584);
    float*          ctxpart  = (float*)(ws + 843776);

    prep_kernel<<<289, 256, 0, stream>>>(query, Q_w, Q_b, conv_w, loc_proj_w, V_w,
                                         qbuf, Bph, Bpl, effh, effl);
    energy_ctx_kernel<<<1024, 512, 0, stream>>>(values, cum, qbuf, Bph, Bpl,
                                                effh, effl, v_w, mask,
                                                wU, bstats, ctxpart);
    combine_kernel<<<B_, 256, 0, stream>>>(bstats, ctxpart, wU, out);
}